// Round 17
// baseline (160.912 us; speedup 1.0000x reference)
//
#include <hip/hip_runtime.h>

#define NN  512    // data grid / coefficient count per axis
#define NE  1024   // eval points per axis
#define NBC 64     // batch * channels
#define WH  5      // truncated-inverse half width (0.268^6 ~ 4e-4 rel err)
#define WT  11     // 2*WH+1 taps
#define XT  256    // x-tile per block
#define YTL 32     // y-tile per block
#define BR  148    // B columns = i' extent (off4<=128 + 20-tap window)
#define BSTR 152   // B row stride, floats (608 B = 16B multiple)
#define ZC  36     // ZwT rows = j'' cols (9 granules)
#define ZSTR 149   // ZwT row stride, floats (odd -> conflict-free)
#define NRB 20     // B rows (CT j-rows per y-tile)

typedef float v4f __attribute__((ext_vector_type(4)));

// ================= compile-time table generation =================
// x = float32 linspace(-1,1,512); knots via float32 cumsum sliding mean;
// basis via de Boor in double; banded LU in double; truncated inverse band
// Gb (half-width 5); W4T = eval x-basis COMPOSED with Gb: 20-tap filter on
// the stage-1 intermediate B, quad-anchored at a4=(espan[q0]-8)&~3, stored
// TRANSPOSED for lane-coalesced loads. Gb/W4T have EXACT ZEROS at tap
// positions whose source column falls outside [0,NN) — boundary handling
// in the kernel is address clamping + zero taps (inputs finite).

struct Tables {
  float Gb[NN][WT];      // truncated A^-1 band
  int   espan[NE];
  float ebas[NE * 4];    // y-combine weights (float4-aligned)
  float W4T[20][NE];     // composed x-filter, transposed
};

constexpr int cfindspan(double u, const float* t) {
  if (u >= (double)t[NN]) return NN - 1;          // t[512] == 1.0
  int lo = 3, hi = NN - 1;
  while (lo < hi) {
    int mid = (lo + hi + 1) >> 1;
    if ((double)t[mid] <= u) lo = mid; else hi = mid - 1;
  }
  return lo;
}

constexpr void cdeboor4(double u, const float* t, int s, double* N) {
  double left[4] = {}, right[4] = {};
  N[0] = 1.0; N[1] = 0.0; N[2] = 0.0; N[3] = 0.0;
  for (int d = 1; d <= 3; ++d) {
    left[d]  = u - (double)t[s + 1 - d];
    right[d] = (double)t[s + d] - u;
    double saved = 0.0;
    for (int r = 0; r < d; ++r) {
      double temp = N[r] / (right[r + 1] + left[d - r]);
      N[r] = saved + right[r + 1] * temp;
      saved = left[d - r] * temp;
    }
    N[d] = saved;
  }
}

constexpr Tables make_tables() {
  Tables T{};
  float x[NN] = {};
  for (int i = 0; i < NN; ++i) x[i] = (float)(-1.0 + (2.0 * i) / 511.0);
  x[0] = -1.0f; x[NN - 1] = 1.0f;
  float t[NN + 4] = {};
  {
    float cs[NN + 1] = {};
    for (int i = 0; i < NN; ++i) cs[i + 1] = cs[i] + x[i];
    for (int i = 0; i < NN - 4; ++i) t[4 + i] = (cs[4 + i] - cs[1 + i]) / 3.0f;
    for (int i = 0; i < 4; ++i) { t[i] = -1.0f; t[NN + i] = 1.0f; }
  }
  double W[NN][7] = {};
  for (int r = 0; r < NN; ++r) {
    double u = (double)x[r];
    int s = cfindspan(u, t);
    double N[4] = {};
    cdeboor4(u, t, s, N);
    for (int dd = 0; dd < 4; ++dd) W[r][s - r + dd] += N[dd];
  }
  for (int r = 0; r < NN; ++r) {
    double rd = 1.0 / W[r][3];
    for (int k = 1; k <= 3; ++k) {
      if (r + k < NN) {
        double l = W[r + k][3 - k] * rd;
        W[r + k][3 - k] = l;
        for (int cc = 1; cc <= 3; ++cc) W[r + k][3 - k + cc] -= l * W[r][3 + cc];
      }
    }
  }
  // truncated inverse band (half-width WH)
  double Gbd[NN][WT] = {};
  double tv[WT] = {};
  for (int pass = 0; pass < 3; ++pass) {
    const int ylo = (pass == 0) ? 0 : (pass == 1) ? 480 : 256;
    const int yhi = (pass == 0) ? 32 : (pass == 1) ? 512 : 257;
    for (int y = ylo; y < yhi; ++y) {
      double wv[21] = {};
      int rend = y + 20; if (rend > NN - 1) rend = NN - 1;
      wv[0] = 1.0;
      for (int r = y + 1; r <= rend; ++r) {
        double acc = 0.0;
        if (r - 1 >= y) acc += W[r][2] * wv[r - 1 - y];
        if (r - 2 >= y) acc += W[r][1] * wv[r - 2 - y];
        if (r - 3 >= y) acc += W[r][0] * wv[r - 3 - y];
        wv[r - y] = -acc;
      }
      double g[33] = {};
      int glo = y - WH; if (glo < 0) glo = 0;
      for (int r = rend; r >= glo; --r) {
        double acc = (r >= y) ? wv[r - y] : 0.0;
        if (r + 1 <= rend) acc -= W[r][4] * g[r + 1 - (y - WH)];
        if (r + 2 <= rend) acc -= W[r][5] * g[r + 2 - (y - WH)];
        if (r + 3 <= rend) acc -= W[r][6] * g[r + 3 - (y - WH)];
        g[r - (y - WH)] = acc / W[r][3];
      }
      if (pass == 2) {
        for (int d = 0; d < WT; ++d) tv[d] = g[2 * WH - d];   // Ainv[256+WH-d][256]
      } else {
        int jlo = y - WH; if (jlo < 0) jlo = 0;
        int jhi = y + WH; if (jhi > NN - 1) jhi = NN - 1;
        for (int j = jlo; j <= jhi; ++j) {
          const bool bdry = (pass == 0) ? (j < 24) : (j >= 488);
          if (bdry) Gbd[j][y - j + WH] = g[j - (y - WH)];
        }
      }
    }
  }
  for (int j = 24; j < 488; ++j)
    for (int d = 0; d < WT; ++d) Gbd[j][d] = tv[d];
  for (int j = 0; j < NN; ++j)
    for (int d = 0; d < WT; ++d) T.Gb[j][d] = (float)Gbd[j][d];
  // eval-point basis
  int    s_all[NE] = {};
  double dN[NE][4] = {};
  for (int i = 0; i < NE; ++i) {
    float xe = (float)(-1.0 + (2.0 * i) / 1023.0);
    if (i == 0) xe = -1.0f;
    if (i == NE - 1) xe = 1.0f;
    double u = (double)xe;
    int s = cfindspan(u, t);
    double N[4] = {};
    cdeboor4(u, t, s, N);
    s_all[i] = s;
    for (int k = 0; k < 4; ++k) dN[i][k] = N[k];
    T.espan[i] = s;
    T.ebas[i * 4 + 0] = (float)N[0];
    T.ebas[i * 4 + 1] = (float)N[1];
    T.ebas[i * 4 + 2] = (float)N[2];
    T.ebas[i * 4 + 3] = (float)N[3];
  }
  // W4T[m][x]: out contribution = sum_m W4T[m][x] * B[a4 + m],
  // a4 = (s_all[quad0]-8)&~3; m = (s-3+k) - WH + d - a4, proven in [0,19].
  for (int xx = 0; xx < NE; ++xx) {
    const int a4 = (s_all[(xx >> 2) << 2] - 8) & ~3;
    double acc[20] = {};
    for (int k = 0; k < 4; ++k) {
      const int i = s_all[xx] - 3 + k;
      for (int d = 0; d < WT; ++d) {
        const int m = i - WH + d - a4;
        acc[m] += dN[xx][k] * Gbd[i][d];
      }
    }
    for (int m = 0; m < 20; ++m) T.W4T[m][xx] = (float)acc[m];
  }
  return T;
}

__constant__ Tables g_tab = make_tables();

// ------------- fully fused kernel, v2 -------------
// Per block: output tile 32 y-rows x 256 x-cols for one bc.
//   phase 0: stage Z window TRANSPOSED: ZwT[j''][i'] (36 x 148), clamped
//   phase 1: B[jr][i'] = 11-tap Gb contraction along j (thread = i'-row;
//            reads ZwT[c][tid] -> consecutive lanes -> conflict-free)
//   phase 2: sliding-P eval from B via composed 20-tap W4T filter
// 2 barriers; no global intermediate; boundary = clamp + constexpr zero taps.

__global__ __launch_bounds__(256) void k_fused2(const float* __restrict__ Z,
                                                float* __restrict__ out) {
  const int bx = blockIdx.x;            // 128 = 4 x-tiles x 32 y-tiles
  const int xt = (bx & 3) * XT;
  const int y0 = (bx >> 2) * YTL;
  const int bc = blockIdx.y;
  const float* __restrict__ src = Z + (size_t)bc * (NN * NN);

  const int rlo = g_tab.espan[y0] - 3;          // CT j-row window start (20 rows)
  const int ibB = (g_tab.espan[xt] - 8) & ~3;   // i'-window start (4-aligned)
  const int g0  = (rlo - WH) & ~3;              // j''-granule base
  const int coff = (rlo - WH) - g0;             // 0..3, block-uniform

  __shared__ float ZwT[ZC][ZSTR];       // 21.5 KB, transposed Z window
  __shared__ float B[NRB][BSTR];        // 12.2 KB
  const int tid = threadIdx.x;

  // ---- phase 0: load + transpose (granule/row clamp; garbage hits zero taps)
  for (int u = tid; u < BR * 9; u += 256) {
    const int rr = u / 9, g = u % 9;
    int gi = ibB + rr;
    gi = (gi < 0) ? 0 : ((gi > NN - 1) ? NN - 1 : gi);
    int gj = g0 + 4 * g;
    gj = (gj < 0) ? 0 : ((gj > NN - 4) ? NN - 4 : gj);
    const float4 v = *(const float4*)&src[(size_t)gi * NN + gj];
    ZwT[4 * g + 0][rr] = v.x;
    ZwT[4 * g + 1][rr] = v.y;
    ZwT[4 * g + 2][rr] = v.z;
    ZwT[4 * g + 3][rr] = v.w;
  }
  __syncthreads();

  // ---- phase 1: 11-tap j-contraction, thread = i'-row (conflict-free reads)
  if (tid < BR) {
    float w2[30];                       // cols coff..coff+29 (static per branch)
    if (coff == 0) {
      #pragma unroll
      for (int c = 0; c < 30; ++c) w2[c] = ZwT[c + 0][tid];
    } else if (coff == 1) {
      #pragma unroll
      for (int c = 0; c < 30; ++c) w2[c] = ZwT[c + 1][tid];
    } else if (coff == 2) {
      #pragma unroll
      for (int c = 0; c < 30; ++c) w2[c] = ZwT[c + 2][tid];
    } else {
      #pragma unroll
      for (int c = 0; c < 30; ++c) w2[c] = ZwT[c + 3][tid];
    }
    #pragma unroll 1
    for (int jr = 0; jr < NRB; ++jr) {
      const float* __restrict__ gr = g_tab.Gb[rlo + jr];   // wave-uniform scalar
      float acc = 0.f;
      #pragma unroll
      for (int e = 0; e < WT; ++e) acc += gr[e] * w2[jr + e];
      B[jr][tid] = acc;
    }
  }
  __syncthreads();

  // ---- phase 2: sliding-P eval; thread = (x-quad, y-octet)
  const int xq = tid & 63, yg = tid >> 6;
  const int x0 = xt + xq * 4;
  const int a4 = (g_tab.espan[x0] - 8) & ~3;
  const int off4 = a4 - ibB;                    // 4-aligned, in [0, 128]
  float tp[4][20];
  #pragma unroll
  for (int m = 0; m < 20; ++m)
    #pragma unroll
    for (int e = 0; e < 4; ++e)
      tp[e][m] = g_tab.W4T[m][x0 + e];          // lane-coalesced

  auto filterP = [&](int r) -> v4f {
    float w[20];
    #pragma unroll
    for (int e = 0; e < 5; ++e)
      *(float4*)&w[e * 4] = *(const float4*)&B[r][off4 + e * 4];  // 16B-aligned
    v4f p;
    #pragma unroll
    for (int e = 0; e < 4; ++e) {
      float s0 = 0.f, s1 = 0.f;
      #pragma unroll
      for (int m = 0; m < 20; m += 2) {
        s0 += tp[e][m]     * w[m];
        s1 += tp[e][m + 1] * w[m + 1];
      }
      p[e] = s0 + s1;
    }
    return p;
  };

  const int k0 = y0 + yg * 8;                   // this thread's 8 y-rows
  int prev = g_tab.espan[k0] - rlo;             // 3..16; window rows prev-3..prev
  v4f P0 = filterP(prev - 3), P1 = filterP(prev - 2),
      P2 = filterP(prev - 1), P3 = filterP(prev);
  float* __restrict__ O0 = out + ((size_t)bc * NE + k0) * NE + x0;
  #pragma unroll 1
  for (int kk = 0; kk < 8; ++kk) {
    const int ry = g_tab.espan[k0 + kk] - rlo;  // wave-uniform; advances 0/1
    if (ry != prev) {
      P0 = P1; P1 = P2; P2 = P3;
      P3 = filterP(ry);
      prev = ry;
    }
    const float4 wy = *(const float4*)&g_tab.ebas[(k0 + kk) * 4];
    v4f o;
    #pragma unroll
    for (int e = 0; e < 4; ++e)
      o[e] = wy.x * P0[e] + wy.y * P1[e] + wy.z * P2[e] + wy.w * P3[e];
    *(v4f*)&O0[(size_t)kk * NE] = o;
  }
}

// ---------------- host launcher ----------------

extern "C" void kernel_launch(void* const* d_in, const int* in_sizes, int n_in,
                              void* d_out, int out_size, void* d_ws, size_t ws_size,
                              hipStream_t stream) {
  (void)in_sizes; (void)n_in; (void)out_size; (void)d_ws; (void)ws_size;
  const float* Z = (const float*)d_in[0];
  float* out = (float*)d_out;
  k_fused2<<<dim3(128, NBC), 256, 0, stream>>>(Z, out);   // single fused kernel
}

// Round 18
// 114.056 us; speedup vs baseline: 1.4108x; 1.4108x over previous
//
#include <hip/hip_runtime.h>
#include <hip/hip_bf16.h>

#define NN  512    // data grid / coefficient count per axis
#define NE  1024   // eval points per axis
#define NBC 64     // batch * channels
#define WH  6      // truncated-inverse half width (0.268^7 ~ 1e-4 rel err)
#define WT  13     // 2*WH+1 taps
#define YT  64     // y-tile per eval block

typedef float v4f __attribute__((ext_vector_type(4)));

// ================= compile-time table generation =================
// x = float32 linspace(-1,1,512); knots via float32 cumsum sliding mean;
// basis via de Boor in double; banded LU in double; truncated inverse band
// Gb (half-width 6) for BOTH solve directions; W3T = 4-tap eval basis
// re-anchored to a per-quad aligned 12-tap window, stored TRANSPOSED for
// lane-coalesced loads. Gb rows and W3T have EXACT ZEROS at tap positions
// whose source column falls outside the true span — boundary handling is
// address clamping + zero taps.

struct Tables {
  float Gb[NN][WT];      // truncated A^-1 band
  int   espan[NE];
  float ebas[NE * 4];    // y-combine weights (float4-aligned)
  float W3T[12][NE];     // anchored 4-tap x-filter, transposed
};

constexpr int cfindspan(double u, const float* t) {
  if (u >= (double)t[NN]) return NN - 1;          // t[512] == 1.0
  int lo = 3, hi = NN - 1;
  while (lo < hi) {
    int mid = (lo + hi + 1) >> 1;
    if ((double)t[mid] <= u) lo = mid; else hi = mid - 1;
  }
  return lo;
}

constexpr void cdeboor4(double u, const float* t, int s, double* N) {
  double left[4] = {}, right[4] = {};
  N[0] = 1.0; N[1] = 0.0; N[2] = 0.0; N[3] = 0.0;
  for (int d = 1; d <= 3; ++d) {
    left[d]  = u - (double)t[s + 1 - d];
    right[d] = (double)t[s + d] - u;
    double saved = 0.0;
    for (int r = 0; r < d; ++r) {
      double temp = N[r] / (right[r + 1] + left[d - r]);
      N[r] = saved + right[r + 1] * temp;
      saved = left[d - r] * temp;
    }
    N[d] = saved;
  }
}

constexpr Tables make_tables() {
  Tables T{};
  float x[NN] = {};
  for (int i = 0; i < NN; ++i) x[i] = (float)(-1.0 + (2.0 * i) / 511.0);
  x[0] = -1.0f; x[NN - 1] = 1.0f;
  float t[NN + 4] = {};
  {
    float cs[NN + 1] = {};
    for (int i = 0; i < NN; ++i) cs[i + 1] = cs[i] + x[i];
    for (int i = 0; i < NN - 4; ++i) t[4 + i] = (cs[4 + i] - cs[1 + i]) / 3.0f;
    for (int i = 0; i < 4; ++i) { t[i] = -1.0f; t[NN + i] = 1.0f; }
  }
  double W[NN][7] = {};
  for (int r = 0; r < NN; ++r) {
    double u = (double)x[r];
    int s = cfindspan(u, t);
    double N[4] = {};
    cdeboor4(u, t, s, N);
    for (int dd = 0; dd < 4; ++dd) W[r][s - r + dd] += N[dd];
  }
  for (int r = 0; r < NN; ++r) {
    double rd = 1.0 / W[r][3];
    for (int k = 1; k <= 3; ++k) {
      if (r + k < NN) {
        double l = W[r + k][3 - k] * rd;
        W[r + k][3 - k] = l;
        for (int cc = 1; cc <= 3; ++cc) W[r + k][3 - k + cc] -= l * W[r][3 + cc];
      }
    }
  }
  // truncated inverse band (half-width WH)
  double Gbd[NN][WT] = {};
  double tv[WT] = {};
  for (int pass = 0; pass < 3; ++pass) {
    const int ylo = (pass == 0) ? 0 : (pass == 1) ? 480 : 256;
    const int yhi = (pass == 0) ? 32 : (pass == 1) ? 512 : 257;
    for (int y = ylo; y < yhi; ++y) {
      double wv[21] = {};
      int rend = y + 20; if (rend > NN - 1) rend = NN - 1;
      wv[0] = 1.0;
      for (int r = y + 1; r <= rend; ++r) {
        double acc = 0.0;
        if (r - 1 >= y) acc += W[r][2] * wv[r - 1 - y];
        if (r - 2 >= y) acc += W[r][1] * wv[r - 2 - y];
        if (r - 3 >= y) acc += W[r][0] * wv[r - 3 - y];
        wv[r - y] = -acc;
      }
      double g[33] = {};
      int glo = y - WH; if (glo < 0) glo = 0;
      for (int r = rend; r >= glo; --r) {
        double acc = (r >= y) ? wv[r - y] : 0.0;
        if (r + 1 <= rend) acc -= W[r][4] * g[r + 1 - (y - WH)];
        if (r + 2 <= rend) acc -= W[r][5] * g[r + 2 - (y - WH)];
        if (r + 3 <= rend) acc -= W[r][6] * g[r + 3 - (y - WH)];
        g[r - (y - WH)] = acc / W[r][3];
      }
      if (pass == 2) {
        for (int d = 0; d < WT; ++d) tv[d] = g[2 * WH - d];   // Ainv[256+WH-d][256]
      } else {
        int jlo = y - WH; if (jlo < 0) jlo = 0;
        int jhi = y + WH; if (jhi > NN - 1) jhi = NN - 1;
        for (int j = jlo; j <= jhi; ++j) {
          const bool bdry = (pass == 0) ? (j < 24) : (j >= 488);
          if (bdry) Gbd[j][y - j + WH] = g[j - (y - WH)];
        }
      }
    }
  }
  for (int j = 24; j < 488; ++j)
    for (int d = 0; d < WT; ++d) Gbd[j][d] = tv[d];
  for (int j = 0; j < NN; ++j)
    for (int d = 0; d < WT; ++d) T.Gb[j][d] = (float)Gbd[j][d];
  // eval-point basis + anchored transposed 12-tap x-filter
  int    s_all[NE] = {};
  double dN[NE][4] = {};
  for (int i = 0; i < NE; ++i) {
    float xe = (float)(-1.0 + (2.0 * i) / 1023.0);
    if (i == 0) xe = -1.0f;
    if (i == NE - 1) xe = 1.0f;
    double u = (double)xe;
    int s = cfindspan(u, t);
    double N[4] = {};
    cdeboor4(u, t, s, N);
    s_all[i] = s;
    for (int k = 0; k < 4; ++k) dN[i][k] = N[k];
    T.espan[i] = s;
    T.ebas[i * 4 + 0] = (float)N[0];
    T.ebas[i * 4 + 1] = (float)N[1];
    T.ebas[i * 4 + 2] = (float)N[2];
    T.ebas[i * 4 + 3] = (float)N[3];
  }
  // W3T[m][x]: out[x] = sum_m W3T[m][x] * CTrow[a3 + m], a3 = (s_all[quad0]-3)&~3.
  for (int xx = 0; xx < NE; ++xx) {
    const int a3 = (s_all[(xx >> 2) << 2] - 3) & ~3;
    for (int k = 0; k < 4; ++k) {
      const int m = s_all[xx] - 3 + k - a3;
      T.W3T[m][xx] = (float)dN[xx][k];
    }
  }
  return T;
}

__constant__ Tables g_tab = make_tables();

__device__ __forceinline__ unsigned short f2bf(float f) {
  __hip_bfloat16 h = __float2bfloat16(f);              // round-to-nearest-even
  return reinterpret_cast<const unsigned short&>(h);
}

// ------------- K1: full 2D banded solve, register-staged stage 1 -------------
// CT[bc][j][i] (BF16) = sum_{d,e} Gb[i][d]*Gb[j][e]*Z[bc][i-WH+d][j-WH+e]
// Stage 1 reads Z windows DIRECTLY from global (coalesced 256B groups, L1/L2
// served redundancy); boundary = address clamp + zero taps. 13-tap window for
// j-quad q: w[q+2..q+14] of the 20-float granule window based at quad-8.
// Only LDS is the transposed stage-1 At (22.8 KB) -> 1 barrier.

__global__ __launch_bounds__(256) void k_solve2d(const float* __restrict__ Z,
                                                 unsigned short* __restrict__ CT) {
  const int it = blockIdx.x * 64;
  const int jt = blockIdx.y * 64;
  const int bc = blockIdx.z;
  const float* __restrict__ src = Z + (size_t)bc * (NN * NN);
  __shared__ float At[64][89];   // stage-1 result TRANSPOSED: At[jc][ii]
  const int tid = threadIdx.x;
  const int q4 = (tid & 15) * 4;    // quad base (jc for stage1, ic for stage2)

  { // stage 1: 13-tap along j, 80 i-rows, straight from global
    float cy[4][WT];
    #pragma unroll
    for (int q = 0; q < 4; ++q)
      #pragma unroll
      for (int d = 0; d < WT; ++d)
        cy[q][d] = g_tab.Gb[jt + q4 + q][d];
    #pragma unroll 1
    for (int p = 0; p < 5; ++p) {
      const int ii = p * 16 + (tid >> 4);
      int gi = it - 8 + ii;
      gi = (gi < 0) ? 0 : ((gi > NN - 1) ? NN - 1 : gi);   // clamp: garbage killed by stage-2 zero taps
      const float* __restrict__ rowp = &src[(size_t)gi * NN];
      float w[20];
      #pragma unroll
      for (int e = 0; e < 5; ++e) {
        int gj = jt + q4 - 8 + e * 4;                       // 4-aligned granule
        gj = (gj < 0) ? 0 : ((gj > NN - 4) ? NN - 4 : gj);  // clamp: dead granules hit zero taps
        *(float4*)&w[e * 4] = *(const float4*)&rowp[gj];
      }
      float4 a = make_float4(0.f, 0.f, 0.f, 0.f);
      #pragma unroll
      for (int d = 0; d < WT; ++d) {
        a.x += cy[0][d] * w[2 + d];
        a.y += cy[1][d] * w[3 + d];
        a.z += cy[2][d] * w[4 + d];
        a.w += cy[3][d] * w[5 + d];
      }
      At[q4 + 0][ii] = a.x;
      At[q4 + 1][ii] = a.y;
      At[q4 + 2][ii] = a.z;
      At[q4 + 3][ii] = a.w;
    }
  }
  { // stage 2: 13-tap along i; coalesced bf16 writes
    float cx[4][WT];
    #pragma unroll
    for (int q = 0; q < 4; ++q)
      #pragma unroll
      for (int d = 0; d < WT; ++d)
        cx[q][d] = g_tab.Gb[it + q4 + q][d];
    __syncthreads();
    unsigned short* __restrict__ dst = CT + (size_t)bc * (NN * NN);
    #pragma unroll 1
    for (int p = 0; p < 4; ++p) {
      const int jc = p * 16 + (tid >> 4);
      float w[20];
      #pragma unroll
      for (int e = 0; e < 5; ++e)
        *(float4*)&w[e * 4] = *(const float4*)&At[jc][q4 + e * 4];
      float4 a = make_float4(0.f, 0.f, 0.f, 0.f);
      #pragma unroll
      for (int d = 0; d < WT; ++d) {
        a.x += cx[0][d] * w[2 + d];
        a.y += cx[1][d] * w[3 + d];
        a.z += cx[2][d] * w[4 + d];
        a.w += cx[3][d] * w[5 + d];
      }
      ushort4 o;
      o.x = f2bf(a.x); o.y = f2bf(a.y); o.z = f2bf(a.z); o.w = f2bf(a.w);
      *(ushort4*)&dst[(size_t)(jt + jc) * NN + it + q4] = o;   // 8B aligned
    }
  }
}

// ------------- K2: LDS-free sliding-P eval with 2-DEEP ROW PREFETCH -------------
// P[r] = anchored 12-tap x-filter of CT row r at this thread's x-quad, read
// directly from global. The slide row is always prev+1, so raw uint2 triplets
// for rows prev+1 and prev+2 are PREFETCHED into registers; a slide consumes
// pfA (in flight for >= 2 slide-intervals) -> gather latency fully hidden.
// No LDS, no barrier; slides are block-uniform; row index clamped to NN-1.

struct Pf { uint2 a, b, c; };

__global__ __launch_bounds__(256) void k_eval10(const unsigned short* __restrict__ CT,
                                                float* __restrict__ out) {
  const int b = blockIdx.x;                         // 16 y-tiles
  const int ytile = ((b & 7) << 1) | (b >> 3);      // XCD-chunked swizzle (bijective, 16)
  const int y0 = ytile * YT;
  const int bc = blockIdx.y;
  const unsigned short* __restrict__ S = CT + (size_t)bc * (NN * NN);
  const int tid = threadIdx.x;

  // hoisted per-thread constants (lane-coalesced via transposed W3T)
  const int x0 = tid * 4;
  const int a3 = (g_tab.espan[x0] - 3) & ~3;        // window base (mult of 4 -> 8B aligned)
  float tp[4][12];
  #pragma unroll
  for (int m = 0; m < 12; ++m)
    #pragma unroll
    for (int e = 0; e < 4; ++e)
      tp[e][m] = g_tab.W3T[m][x0 + e];

  auto loadRow = [&](int r) -> Pf {
    r = (r > NN - 1) ? NN - 1 : r;                  // clamp (tail prefetches unused)
    const unsigned short* __restrict__ rp = &S[(size_t)r * NN + a3];
    Pf f;
    f.a = *(const uint2*)&rp[0];
    f.b = *(const uint2*)&rp[4];
    f.c = *(const uint2*)&rp[8];
    return f;
  };
  auto filt = [&](Pf f) -> v4f {
    float w[12];
    w[0]  = __uint_as_float(f.a.x << 16); w[1]  = __uint_as_float(f.a.x & 0xffff0000u);
    w[2]  = __uint_as_float(f.a.y << 16); w[3]  = __uint_as_float(f.a.y & 0xffff0000u);
    w[4]  = __uint_as_float(f.b.x << 16); w[5]  = __uint_as_float(f.b.x & 0xffff0000u);
    w[6]  = __uint_as_float(f.b.y << 16); w[7]  = __uint_as_float(f.b.y & 0xffff0000u);
    w[8]  = __uint_as_float(f.c.x << 16); w[9]  = __uint_as_float(f.c.x & 0xffff0000u);
    w[10] = __uint_as_float(f.c.y << 16); w[11] = __uint_as_float(f.c.y & 0xffff0000u);
    v4f p;
    #pragma unroll
    for (int e = 0; e < 4; ++e) {
      float s0 = 0.f, s1 = 0.f;
      #pragma unroll
      for (int m = 0; m < 12; m += 2) {
        s0 += tp[e][m]     * w[m];
        s1 += tp[e][m + 1] * w[m + 1];
      }
      p[e] = s0 + s1;
    }
    return p;
  };

  // initial window + 2-deep prefetch (all 6 row loads issued back-to-back)
  int prev = g_tab.espan[y0];
  Pf f0 = loadRow(prev - 3), f1 = loadRow(prev - 2),
     f2 = loadRow(prev - 1), f3 = loadRow(prev);
  Pf pfA = loadRow(prev + 1), pfB = loadRow(prev + 2);
  v4f P0 = filt(f0), P1 = filt(f1), P2 = filt(f2), P3 = filt(f3);

  float* __restrict__ O0 = out + ((size_t)bc * NE + y0) * NE + x0;
  #pragma unroll 1
  for (int k = 0; k < YT; ++k) {
    const int ry = g_tab.espan[y0 + k];             // block-uniform; advances 0 or 1
    if (ry != prev) {                               // slide: consume prefetched row
      P0 = P1; P1 = P2; P2 = P3;
      P3 = filt(pfA);
      pfA = pfB;
      pfB = loadRow(ry + 2);                        // refill pipeline
      prev = ry;
    }
    const float4 wy = *(const float4*)&g_tab.ebas[(y0 + k) * 4];
    v4f o;
    #pragma unroll
    for (int e = 0; e < 4; ++e)
      o[e] = wy.x * P0[e] + wy.y * P1[e] + wy.z * P2[e] + wy.w * P3[e];
    *(v4f*)&O0[(size_t)k * NE] = o;
  }
}

// ---------------- host launcher ----------------

extern "C" void kernel_launch(void* const* d_in, const int* in_sizes, int n_in,
                              void* d_out, int out_size, void* d_ws, size_t ws_size,
                              hipStream_t stream) {
  (void)in_sizes; (void)n_in; (void)out_size; (void)ws_size;
  const float* Z = (const float*)d_in[0];
  float* out = (float*)d_out;
  unsigned short* CT = (unsigned short*)d_ws;   // 32 MB bf16 coefficients

  k_solve2d<<<dim3(8, 8, NBC),    256, 0, stream>>>(Z,  CT);   // 2D banded solve -> bf16 CT
  k_eval10 <<<dim3(NE / YT, NBC), 256, 0, stream>>>(CT, out);  // prefetched sliding-P eval
}

// Round 19
// 110.171 us; speedup vs baseline: 1.4606x; 1.0353x over previous
//
#include <hip/hip_runtime.h>
#include <hip/hip_bf16.h>

#define NN  512    // data grid / coefficient count per axis
#define NE  1024   // eval points per axis
#define NBC 64     // batch * channels
#define WH  6      // truncated-inverse half width (0.268^7 ~ 1e-4 rel err)
#define WT  13     // 2*WH+1 taps
#define YT  32     // y-tile per eval block

typedef float v4f __attribute__((ext_vector_type(4)));

// ================= compile-time table generation =================
// x = float32 linspace(-1,1,512); knots via float32 cumsum sliding mean;
// basis via de Boor in double; banded LU in double; truncated inverse band
// Gb (half-width 6) for BOTH solve directions; W3T = 4-tap eval basis
// re-anchored to a per-quad aligned 12-tap window, stored TRANSPOSED for
// lane-coalesced loads; smask = per-y-tile slide bitmask (bit k: the P
// window advances at local row k). Gb rows and W3T have EXACT ZEROS at tap
// positions whose source column falls outside the true span — boundary
// handling is address clamping + zero taps.

struct Tables {
  float Gb[NN][WT];      // truncated A^-1 band
  int   espan[NE];
  float ebas[NE * 4];    // y-combine weights (float4-aligned)
  float W3T[12][NE];     // anchored 4-tap x-filter, transposed
  unsigned int smask[NE / YT];  // slide bitmask per y-tile
};

constexpr int cfindspan(double u, const float* t) {
  if (u >= (double)t[NN]) return NN - 1;          // t[512] == 1.0
  int lo = 3, hi = NN - 1;
  while (lo < hi) {
    int mid = (lo + hi + 1) >> 1;
    if ((double)t[mid] <= u) lo = mid; else hi = mid - 1;
  }
  return lo;
}

constexpr void cdeboor4(double u, const float* t, int s, double* N) {
  double left[4] = {}, right[4] = {};
  N[0] = 1.0; N[1] = 0.0; N[2] = 0.0; N[3] = 0.0;
  for (int d = 1; d <= 3; ++d) {
    left[d]  = u - (double)t[s + 1 - d];
    right[d] = (double)t[s + d] - u;
    double saved = 0.0;
    for (int r = 0; r < d; ++r) {
      double temp = N[r] / (right[r + 1] + left[d - r]);
      N[r] = saved + right[r + 1] * temp;
      saved = left[d - r] * temp;
    }
    N[d] = saved;
  }
}

constexpr Tables make_tables() {
  Tables T{};
  float x[NN] = {};
  for (int i = 0; i < NN; ++i) x[i] = (float)(-1.0 + (2.0 * i) / 511.0);
  x[0] = -1.0f; x[NN - 1] = 1.0f;
  float t[NN + 4] = {};
  {
    float cs[NN + 1] = {};
    for (int i = 0; i < NN; ++i) cs[i + 1] = cs[i] + x[i];
    for (int i = 0; i < NN - 4; ++i) t[4 + i] = (cs[4 + i] - cs[1 + i]) / 3.0f;
    for (int i = 0; i < 4; ++i) { t[i] = -1.0f; t[NN + i] = 1.0f; }
  }
  double W[NN][7] = {};
  for (int r = 0; r < NN; ++r) {
    double u = (double)x[r];
    int s = cfindspan(u, t);
    double N[4] = {};
    cdeboor4(u, t, s, N);
    for (int dd = 0; dd < 4; ++dd) W[r][s - r + dd] += N[dd];
  }
  for (int r = 0; r < NN; ++r) {
    double rd = 1.0 / W[r][3];
    for (int k = 1; k <= 3; ++k) {
      if (r + k < NN) {
        double l = W[r + k][3 - k] * rd;
        W[r + k][3 - k] = l;
        for (int cc = 1; cc <= 3; ++cc) W[r + k][3 - k + cc] -= l * W[r][3 + cc];
      }
    }
  }
  // truncated inverse band (half-width WH)
  double Gbd[NN][WT] = {};
  double tv[WT] = {};
  for (int pass = 0; pass < 3; ++pass) {
    const int ylo = (pass == 0) ? 0 : (pass == 1) ? 480 : 256;
    const int yhi = (pass == 0) ? 32 : (pass == 1) ? 512 : 257;
    for (int y = ylo; y < yhi; ++y) {
      double wv[21] = {};
      int rend = y + 20; if (rend > NN - 1) rend = NN - 1;
      wv[0] = 1.0;
      for (int r = y + 1; r <= rend; ++r) {
        double acc = 0.0;
        if (r - 1 >= y) acc += W[r][2] * wv[r - 1 - y];
        if (r - 2 >= y) acc += W[r][1] * wv[r - 2 - y];
        if (r - 3 >= y) acc += W[r][0] * wv[r - 3 - y];
        wv[r - y] = -acc;
      }
      double g[33] = {};
      int glo = y - WH; if (glo < 0) glo = 0;
      for (int r = rend; r >= glo; --r) {
        double acc = (r >= y) ? wv[r - y] : 0.0;
        if (r + 1 <= rend) acc -= W[r][4] * g[r + 1 - (y - WH)];
        if (r + 2 <= rend) acc -= W[r][5] * g[r + 2 - (y - WH)];
        if (r + 3 <= rend) acc -= W[r][6] * g[r + 3 - (y - WH)];
        g[r - (y - WH)] = acc / W[r][3];
      }
      if (pass == 2) {
        for (int d = 0; d < WT; ++d) tv[d] = g[2 * WH - d];   // Ainv[256+WH-d][256]
      } else {
        int jlo = y - WH; if (jlo < 0) jlo = 0;
        int jhi = y + WH; if (jhi > NN - 1) jhi = NN - 1;
        for (int j = jlo; j <= jhi; ++j) {
          const bool bdry = (pass == 0) ? (j < 24) : (j >= 488);
          if (bdry) Gbd[j][y - j + WH] = g[j - (y - WH)];
        }
      }
    }
  }
  for (int j = 24; j < 488; ++j)
    for (int d = 0; d < WT; ++d) Gbd[j][d] = tv[d];
  for (int j = 0; j < NN; ++j)
    for (int d = 0; d < WT; ++d) T.Gb[j][d] = (float)Gbd[j][d];
  // eval-point basis + anchored transposed 12-tap x-filter
  int    s_all[NE] = {};
  double dN[NE][4] = {};
  for (int i = 0; i < NE; ++i) {
    float xe = (float)(-1.0 + (2.0 * i) / 1023.0);
    if (i == 0) xe = -1.0f;
    if (i == NE - 1) xe = 1.0f;
    double u = (double)xe;
    int s = cfindspan(u, t);
    double N[4] = {};
    cdeboor4(u, t, s, N);
    s_all[i] = s;
    for (int k = 0; k < 4; ++k) dN[i][k] = N[k];
    T.espan[i] = s;
    T.ebas[i * 4 + 0] = (float)N[0];
    T.ebas[i * 4 + 1] = (float)N[1];
    T.ebas[i * 4 + 2] = (float)N[2];
    T.ebas[i * 4 + 3] = (float)N[3];
  }
  // W3T[m][x]: out[x] = sum_m W3T[m][x] * CTrow[a3 + m], a3 = (s_all[quad0]-3)&~3.
  for (int xx = 0; xx < NE; ++xx) {
    const int a3 = (s_all[(xx >> 2) << 2] - 3) & ~3;
    for (int k = 0; k < 4; ++k) {
      const int m = s_all[xx] - 3 + k - a3;
      T.W3T[m][xx] = (float)dN[xx][k];
    }
  }
  // slide bitmask: bit k set iff espan increments at local row k of the tile
  for (int tt = 0; tt < NE / YT; ++tt) {
    unsigned int m = 0u;
    for (int k = 1; k < YT; ++k)
      if (s_all[tt * YT + k] != s_all[tt * YT + k - 1]) m |= (1u << k);
    T.smask[tt] = m;
  }
  return T;
}

__constant__ Tables g_tab = make_tables();

__device__ __forceinline__ unsigned short f2bf(float f) {
  __hip_bfloat16 h = __float2bfloat16(f);              // round-to-nearest-even
  return reinterpret_cast<const unsigned short&>(h);
}

// ------------- K1: full 2D banded solve, register-staged stage 1 -------------
// CT[bc][j][i] (BF16) = sum_{d,e} Gb[i][d]*Gb[j][e]*Z[bc][i-WH+d][j-WH+e]
// Stage 1 reads Z windows DIRECTLY from global; boundary = clamp + zero taps.
// Only LDS is the transposed stage-1 At (22.8 KB) -> 1 barrier. Stores are a
// terminal burst (no exposed store latency) — this kernel runs ~6.8 TB/s.

__global__ __launch_bounds__(256) void k_solve2d(const float* __restrict__ Z,
                                                 unsigned short* __restrict__ CT) {
  const int it = blockIdx.x * 64;
  const int jt = blockIdx.y * 64;
  const int bc = blockIdx.z;
  const float* __restrict__ src = Z + (size_t)bc * (NN * NN);
  __shared__ float At[64][89];   // stage-1 result TRANSPOSED: At[jc][ii]
  const int tid = threadIdx.x;
  const int q4 = (tid & 15) * 4;    // quad base (jc for stage1, ic for stage2)

  { // stage 1: 13-tap along j, 80 i-rows, straight from global
    float cy[4][WT];
    #pragma unroll
    for (int q = 0; q < 4; ++q)
      #pragma unroll
      for (int d = 0; d < WT; ++d)
        cy[q][d] = g_tab.Gb[jt + q4 + q][d];
    #pragma unroll 1
    for (int p = 0; p < 5; ++p) {
      const int ii = p * 16 + (tid >> 4);
      int gi = it - 8 + ii;
      gi = (gi < 0) ? 0 : ((gi > NN - 1) ? NN - 1 : gi);   // clamp: garbage killed by stage-2 zero taps
      const float* __restrict__ rowp = &src[(size_t)gi * NN];
      float w[20];
      #pragma unroll
      for (int e = 0; e < 5; ++e) {
        int gj = jt + q4 - 8 + e * 4;                       // 4-aligned granule
        gj = (gj < 0) ? 0 : ((gj > NN - 4) ? NN - 4 : gj);  // clamp: dead granules hit zero taps
        *(float4*)&w[e * 4] = *(const float4*)&rowp[gj];
      }
      float4 a = make_float4(0.f, 0.f, 0.f, 0.f);
      #pragma unroll
      for (int d = 0; d < WT; ++d) {
        a.x += cy[0][d] * w[2 + d];
        a.y += cy[1][d] * w[3 + d];
        a.z += cy[2][d] * w[4 + d];
        a.w += cy[3][d] * w[5 + d];
      }
      At[q4 + 0][ii] = a.x;
      At[q4 + 1][ii] = a.y;
      At[q4 + 2][ii] = a.z;
      At[q4 + 3][ii] = a.w;
    }
  }
  { // stage 2: 13-tap along i; coalesced bf16 writes
    float cx[4][WT];
    #pragma unroll
    for (int q = 0; q < 4; ++q)
      #pragma unroll
      for (int d = 0; d < WT; ++d)
        cx[q][d] = g_tab.Gb[it + q4 + q][d];
    __syncthreads();
    unsigned short* __restrict__ dst = CT + (size_t)bc * (NN * NN);
    #pragma unroll 1
    for (int p = 0; p < 4; ++p) {
      const int jc = p * 16 + (tid >> 4);
      float w[20];
      #pragma unroll
      for (int e = 0; e < 5; ++e)
        *(float4*)&w[e * 4] = *(const float4*)&At[jc][q4 + e * 4];
      float4 a = make_float4(0.f, 0.f, 0.f, 0.f);
      #pragma unroll
      for (int d = 0; d < WT; ++d) {
        a.x += cx[0][d] * w[2 + d];
        a.y += cx[1][d] * w[3 + d];
        a.z += cx[2][d] * w[4 + d];
        a.w += cx[3][d] * w[5 + d];
      }
      ushort4 o;
      o.x = f2bf(a.x); o.y = f2bf(a.y); o.z = f2bf(a.z); o.w = f2bf(a.w);
      *(ushort4*)&dst[(size_t)(jt + jc) * NN + it + q4] = o;   // 8B aligned
    }
  }
}

// ------------- K2: batched-store sliding-P eval (bf16 CT, LDS-free) -------------
// Computes 8 output rows into registers, then bursts 8 stores back-to-back:
// the store-data register-overwrite hazard (s_waitcnt vmcnt before rewriting
// the o regs) fires once per 8 stores instead of every store. Slide schedule
// comes from a constexpr bitmask in an SGPR (no per-iteration scalar load /
// dependent branch chain). Slide rows prefetched 2 deep (pfA/pfB).

struct Pf { uint2 a, b, c; };

__global__ __launch_bounds__(256) void k_eval11(const unsigned short* __restrict__ CT,
                                                float* __restrict__ out) {
  const int b = blockIdx.x;                         // 32 y-tiles
  const int ytile = ((b & 7) << 2) | (b >> 3);      // XCD-chunked swizzle (bijective, 32)
  const int y0 = ytile * YT;
  const int bc = blockIdx.y;
  const unsigned short* __restrict__ S = CT + (size_t)bc * (NN * NN);
  const int tid = threadIdx.x;

  // hoisted per-thread constants (lane-coalesced via transposed W3T)
  const int x0 = tid * 4;
  const int a3 = (g_tab.espan[x0] - 3) & ~3;        // window base (mult of 4 -> 8B aligned)
  float tp[4][12];
  #pragma unroll
  for (int m = 0; m < 12; ++m)
    #pragma unroll
    for (int e = 0; e < 4; ++e)
      tp[e][m] = g_tab.W3T[m][x0 + e];

  auto loadRow = [&](int r) -> Pf {
    r = (r > NN - 1) ? NN - 1 : r;                  // clamp (tail prefetches unused)
    const unsigned short* __restrict__ rp = &S[(size_t)r * NN + a3];
    Pf f;
    f.a = *(const uint2*)&rp[0];
    f.b = *(const uint2*)&rp[4];
    f.c = *(const uint2*)&rp[8];
    return f;
  };
  auto filt = [&](Pf f) -> v4f {
    float w[12];
    w[0]  = __uint_as_float(f.a.x << 16); w[1]  = __uint_as_float(f.a.x & 0xffff0000u);
    w[2]  = __uint_as_float(f.a.y << 16); w[3]  = __uint_as_float(f.a.y & 0xffff0000u);
    w[4]  = __uint_as_float(f.b.x << 16); w[5]  = __uint_as_float(f.b.x & 0xffff0000u);
    w[6]  = __uint_as_float(f.b.y << 16); w[7]  = __uint_as_float(f.b.y & 0xffff0000u);
    w[8]  = __uint_as_float(f.c.x << 16); w[9]  = __uint_as_float(f.c.x & 0xffff0000u);
    w[10] = __uint_as_float(f.c.y << 16); w[11] = __uint_as_float(f.c.y & 0xffff0000u);
    v4f p;
    #pragma unroll
    for (int e = 0; e < 4; ++e) {
      float s0 = 0.f, s1 = 0.f;
      #pragma unroll
      for (int m = 0; m < 12; m += 2) {
        s0 += tp[e][m]     * w[m];
        s1 += tp[e][m + 1] * w[m + 1];
      }
      p[e] = s0 + s1;
    }
    return p;
  };

  // initial window + 2-deep prefetch (6 row loads issued back-to-back)
  int prev = g_tab.espan[y0];
  Pf f0 = loadRow(prev - 3), f1 = loadRow(prev - 2),
     f2 = loadRow(prev - 1), f3 = loadRow(prev);
  Pf pfA = loadRow(prev + 1), pfB = loadRow(prev + 2);
  v4f P0 = filt(f0), P1 = filt(f1), P2 = filt(f2), P3 = filt(f3);
  const unsigned int smask = g_tab.smask[ytile];    // SGPR slide schedule

  float* __restrict__ O0 = out + ((size_t)bc * NE + y0) * NE + x0;
  #pragma unroll 1
  for (int bb = 0; bb < YT / 8; ++bb) {
    v4f o[8];
    #pragma unroll
    for (int r = 0; r < 8; ++r) {
      const int k = bb * 8 + r;
      if (smask & (1u << k)) {                      // slide: consume prefetched row
        P0 = P1; P1 = P2; P2 = P3;
        P3 = filt(pfA);
        pfA = pfB;
        prev += 1;
        pfB = loadRow(prev + 2);                    // refill pipeline
      }
      const float4 wy = *(const float4*)&g_tab.ebas[(y0 + k) * 4];
      #pragma unroll
      for (int e = 0; e < 4; ++e)
        o[r][e] = wy.x * P0[e] + wy.y * P1[e] + wy.z * P2[e] + wy.w * P3[e];
    }
    #pragma unroll
    for (int r = 0; r < 8; ++r)
      *(v4f*)&O0[(size_t)(bb * 8 + r) * NE] = o[r]; // burst: hazard once per 8 stores
  }
}

// ---------------- host launcher ----------------

extern "C" void kernel_launch(void* const* d_in, const int* in_sizes, int n_in,
                              void* d_out, int out_size, void* d_ws, size_t ws_size,
                              hipStream_t stream) {
  (void)in_sizes; (void)n_in; (void)out_size; (void)ws_size;
  const float* Z = (const float*)d_in[0];
  float* out = (float*)d_out;
  unsigned short* CT = (unsigned short*)d_ws;   // 32 MB bf16 coefficients

  k_solve2d<<<dim3(8, 8, NBC),    256, 0, stream>>>(Z,  CT);   // 2D banded solve -> bf16 CT
  k_eval11 <<<dim3(NE / YT, NBC), 256, 0, stream>>>(CT, out);  // batched-store eval
}